// Round 3
// baseline (270.798 us; speedup 1.0000x reference)
//
#include <hip/hip_runtime.h>
#include <cstdint>

#define N_NODES 50000
#define N_EDGES 800000
#define F_IN    128
#define N_HEADS 4
#define HEAD_DIM 32
#define F_OUT   128
#define NBLK_SCAN 196                     // ceil(50000/256)
#define PREP_GRID 391

typedef unsigned int uint32;
typedef unsigned short ushort;
typedef __attribute__((ext_vector_type(8))) short short8v;   // 8 bf16 in 4 VGPRs
typedef __attribute__((ext_vector_type(4))) float float4v;

__device__ __forceinline__ ushort f2bf(float f) {
    uint32 u = __float_as_uint(f);
    return (ushort)((u + 0x7FFFu + ((u >> 16) & 1u)) >> 16);   // RNE
}

// ---------------------------------------------------------------------------
// K0: prep — WT_hi/WT_lo (bf16 split of W, transposed to [n][k]) + in-degree
// histogram. Both independent of everything else.
// ---------------------------------------------------------------------------
__global__ __launch_bounds__(256) void k_prep(const float* __restrict__ W,
    const int* __restrict__ ei_to, ushort* __restrict__ WT_hi,
    ushort* __restrict__ WT_lo, int* __restrict__ count)
{
    const int id = blockIdx.x * 256 + threadIdx.x;
    if (id < F_IN * F_OUT) {
        const int n = id & 127, k = id >> 7;
        const float w = W[k * F_OUT + n];          // coalesced over n
        const ushort hi = f2bf(w);
        const float hif = __uint_as_float((uint32)hi << 16);
        const ushort lo = f2bf(w - hif);
        WT_hi[n * F_IN + k] = hi;
        WT_lo[n * F_IN + k] = lo;
    }
    for (int e = id; e < N_EDGES; e += PREP_GRID * 256)
        atomicAdd(&count[ei_to[e]], 1);
}

// ---------------------------------------------------------------------------
// K1: h = x @ W via split-bf16 MFMA (hi*hi + lo*hi + hi*lo ≈ fp32-exact),
// fused alpha_l/alpha_r epilogue from the exact fp32 accumulators.
// One wave per 16-row strip; no LDS, no barriers. 50000 % 16 == 0.
// Layouts (m89/m120-verified): A[m=lane&15][k=quad*8+j], B[k=quad*8+j][n=lane&15],
// C/D: col=lane&15, row=quad*4+reg.
// ---------------------------------------------------------------------------
__global__ __launch_bounds__(256) void k_gemm_mfma(
    const float* __restrict__ x,
    const ushort* __restrict__ WT_hi, const ushort* __restrict__ WT_lo,
    const float* __restrict__ attl, const float* __restrict__ attr,
    ushort* __restrict__ hb, float* __restrict__ aL, float* __restrict__ aR)
{
    const int lane = threadIdx.x & 63;
    const int wv   = threadIdx.x >> 6;
    const int q    = lane >> 4;
    const int c15  = lane & 15;
    const int row0 = blockIdx.x * 64 + wv * 16;
    if (row0 >= N_NODES) return;                  // wave-uniform exit

    // --- A fragments: x rows, split into bf16 hi + lo -----------------------
    const float* xrow = x + (size_t)(row0 + c15) * F_IN + q * 8;
    short8v ahi[4], alo[4];
#pragma unroll
    for (int kt = 0; kt < 4; ++kt) {
        const float4 f0 = *(const float4*)(xrow + kt * 32);
        const float4 f1 = *(const float4*)(xrow + kt * 32 + 4);
        const float fs[8] = {f0.x, f0.y, f0.z, f0.w, f1.x, f1.y, f1.z, f1.w};
#pragma unroll
        for (int j = 0; j < 8; ++j) {
            const ushort hi = f2bf(fs[j]);
            const float hif = __uint_as_float((uint32)hi << 16);
            const ushort lo = f2bf(fs[j] - hif);
            ahi[kt][j] = (short)hi;
            alo[kt][j] = (short)lo;
        }
    }

    float aLacc[4][4] = {{0.f}}, aRacc[4][4] = {{0.f}};

#pragma unroll
    for (int nt = 0; nt < 8; ++nt) {
        float4v acc = {0.f, 0.f, 0.f, 0.f};
        const ushort* bh_base = WT_hi + ((nt * 16 + c15) << 7) + q * 8;
        const ushort* bl_base = WT_lo + ((nt * 16 + c15) << 7) + q * 8;
#pragma unroll
        for (int kt = 0; kt < 4; ++kt) {
            const short8v bh = *(const short8v*)(bh_base + kt * 32);
            const short8v bl = *(const short8v*)(bl_base + kt * 32);
            acc = __builtin_amdgcn_mfma_f32_16x16x32_bf16(ahi[kt], bh, acc, 0, 0, 0);
            acc = __builtin_amdgcn_mfma_f32_16x16x32_bf16(alo[kt], bh, acc, 0, 0, 0);
            acc = __builtin_amdgcn_mfma_f32_16x16x32_bf16(ahi[kt], bl, acc, 0, 0, 0);
        }
        // epilogue for this 16-col tile
        const float alv = attl[nt * 16 + c15];    // attl flat [H*D]: idx = nt*16+c15
        const float arv = attr[nt * 16 + c15];
        const int hh = nt >> 1;                   // head of this col tile (constexpr)
#pragma unroll
        for (int r = 0; r < 4; ++r) {
            aLacc[r][hh] = fmaf(acc[r], alv, aLacc[r][hh]);
            aRacc[r][hh] = fmaf(acc[r], arv, aRacc[r][hh]);
            hb[(size_t)(row0 + q * 4 + r) * F_OUT + nt * 16 + c15] = f2bf(acc[r]);
        }
    }

    // --- alpha reduction: sum 16 lanes within each quad ---------------------
#pragma unroll
    for (int r = 0; r < 4; ++r) {
#pragma unroll
        for (int hh = 0; hh < 4; ++hh) {
            float vl = aLacc[r][hh], vr = aRacc[r][hh];
#pragma unroll
            for (int d = 1; d < 16; d <<= 1) {
                vl += __shfl_xor(vl, d);
                vr += __shfl_xor(vr, d);
            }
            if (c15 == hh) {
                const int row = row0 + q * 4 + r;
                aL[row * N_HEADS + hh] = vl;
                aR[row * N_HEADS + hh] = vr;
            }
        }
    }
}

// ---------------------------------------------------------------------------
// 2-level exclusive scan over 50000 counts
// ---------------------------------------------------------------------------
__device__ __forceinline__ int block_scan_excl_256(int v, int* p_total)
{
    const int t = threadIdx.x, lane = t & 63, wv = t >> 6;
    int incl = v;
#pragma unroll
    for (int d = 1; d < 64; d <<= 1) {
        int u = __shfl_up(incl, d);
        if (lane >= d) incl += u;
    }
    __shared__ int wsum[4];
    if (lane == 63) wsum[wv] = incl;
    __syncthreads();
    int woff = 0;
#pragma unroll
    for (int j = 0; j < 4; ++j) {
        int s = wsum[j];
        if (j < wv) woff += s;
    }
    if (p_total) *p_total = wsum[0] + wsum[1] + wsum[2] + wsum[3];
    __syncthreads();
    return woff + incl - v;
}

__global__ __launch_bounds__(256) void k_scan1(const int* __restrict__ count,
                                               int* __restrict__ scanned,
                                               int* __restrict__ blocksum)
{
    int i = blockIdx.x * 256 + threadIdx.x;
    int v = (i < N_NODES) ? count[i] : 0;
    int tot;
    int ex = block_scan_excl_256(v, &tot);
    if (i < N_NODES) scanned[i] = ex;
    if (threadIdx.x == 0) blocksum[blockIdx.x] = tot;
}

__global__ __launch_bounds__(256) void k_scan2(const int* __restrict__ blocksum,
                                               int* __restrict__ blockoff)
{
    int t = threadIdx.x;
    int v = (t < NBLK_SCAN) ? blocksum[t] : 0;
    int ex = block_scan_excl_256(v, nullptr);
    if (t < NBLK_SCAN) blockoff[t] = ex;
}

__global__ __launch_bounds__(256) void k_scan3(const int* __restrict__ scanned,
                                               const int* __restrict__ blockoff,
                                               int* __restrict__ offsets,
                                               int* __restrict__ cursor)
{
    int i = blockIdx.x * 256 + threadIdx.x;
    if (i < N_NODES) {
        int off = scanned[i] + blockoff[blockIdx.x];
        offsets[i] = off;
        cursor[i]  = off;
    }
}

// ---------------------------------------------------------------------------
// K4: scatter edge source ids into destination-sorted CSR order.
// ---------------------------------------------------------------------------
__global__ __launch_bounds__(256) void k_scatter(const int* __restrict__ ei,
    int* __restrict__ cursor, int* __restrict__ rec_from)
{
    int e = blockIdx.x * 256 + threadIdx.x;
    if (e >= N_EDGES) return;
    int from = ei[e], to = ei[N_EDGES + e];
    int pos = atomicAdd(&cursor[to], 1);
    rec_from[pos] = from;
}

// ---------------------------------------------------------------------------
// K5: pull aggregation, one wave per node, lane owns 2 dims (bf16 h gather).
// Softmax max-shift cancels in ex/sum(ex); att <= ~10 so no fp32 overflow.
// ---------------------------------------------------------------------------
__global__ __launch_bounds__(256) void k_agg(const int* __restrict__ rec_from,
    const int* __restrict__ count, const int* __restrict__ offsets,
    const float* __restrict__ aL, const float* __restrict__ aR,
    const ushort* __restrict__ hb,
    const float* __restrict__ bias, float* __restrict__ out)
{
    const int lane = threadIdx.x & 63;
    const int n = blockIdx.x * 4 + (threadIdx.x >> 6);
    if (n >= N_NODES) return;
    const int cnt = count[n];
    const int off = offsets[n];
    const int head = lane >> 4;               // (2*lane)/32
    const float arv = aR[n * N_HEADS + head];
    float ax = 0.f, ay = 0.f, ds = 0.f;
    for (int base = 0; base < cnt; base += 64) {
        const int m = min(64, cnt - base);
        int vf = 0;
        if (lane < m) vf = rec_from[off + base + lane];   // coalesced preload
        for (int i = 0; i < m; ++i) {
            const int fi = __shfl(vf, i);
            float a = aL[fi * N_HEADS + head] + arv;
            a = (a > 0.f) ? a : 0.2f * a;
            const float eh = __expf(a);
            const uint32 hv = *(const uint32*)&hb[fi * F_OUT + 2 * lane];
            const float hx = __uint_as_float(hv << 16);
            const float hy = __uint_as_float(hv & 0xFFFF0000u);
            ax = fmaf(eh, hx, ax);
            ay = fmaf(eh, hy, ay);
            ds += eh;
        }
    }
    const float inv = 1.0f / (ds + 1e-9f);
    const float2 b2 = *(const float2*)&bias[2 * lane];
    float2 o;
    o.x = ax * inv + b2.x;
    o.y = ay * inv + b2.y;
    *(float2*)&out[n * F_OUT + 2 * lane] = o;
}

// ---------------------------------------------------------------------------
extern "C" void kernel_launch(void* const* d_in, const int* in_sizes, int n_in,
                              void* d_out, int out_size, void* d_ws, size_t ws_size,
                              hipStream_t stream)
{
    const float* x    = (const float*)d_in[0];
    const int*   ei   = (const int*)d_in[1];
    const float* W    = (const float*)d_in[2];
    const float* attl = (const float*)d_in[3];
    const float* attr = (const float*)d_in[4];
    const float* bias = (const float*)d_in[5];
    float* out = (float*)d_out;

    char* p = (char*)d_ws;
    auto carve = [&](size_t bytes) -> char* {
        char* q = p;
        p += (bytes + 255) & ~size_t(255);
        return q;
    };
    ushort* hb       = (ushort*)carve((size_t)N_NODES * F_OUT * 2);  // 12.8 MB
    ushort* WT_hi    = (ushort*)carve((size_t)F_IN * F_OUT * 2);     // 32 KB
    ushort* WT_lo    = (ushort*)carve((size_t)F_IN * F_OUT * 2);     // 32 KB
    float*  aL       = (float*)carve((size_t)N_NODES * N_HEADS * 4);
    float*  aR       = (float*)carve((size_t)N_NODES * N_HEADS * 4);
    int*    count    = (int*)carve((size_t)N_NODES * 4);
    int*    scanned  = (int*)carve((size_t)N_NODES * 4);
    int*    offsets  = (int*)carve((size_t)N_NODES * 4);
    int*    cursor   = (int*)carve((size_t)N_NODES * 4);
    int*    blocksum = (int*)carve(256 * 4);
    int*    blockoff = (int*)carve(256 * 4);
    int*    rec_from = (int*)carve((size_t)N_EDGES * 4);             // 3.2 MB

    hipMemsetAsync(count, 0, N_NODES * 4, stream);

    k_prep<<<PREP_GRID, 256, 0, stream>>>(W, ei + N_EDGES, WT_hi, WT_lo, count);
    k_gemm_mfma<<<(N_NODES + 63) / 64, 256, 0, stream>>>(x, WT_hi, WT_lo,
                                                         attl, attr, hb, aL, aR);
    k_scan1<<<NBLK_SCAN, 256, 0, stream>>>(count, scanned, blocksum);
    k_scan2<<<1, 256, 0, stream>>>(blocksum, blockoff);
    k_scan3<<<NBLK_SCAN, 256, 0, stream>>>(scanned, blockoff, offsets, cursor);
    k_scatter<<<(N_EDGES + 255) / 256, 256, 0, stream>>>(ei, cursor, rec_from);
    k_agg<<<(N_NODES + 3) / 4, 256, 0, stream>>>(rec_from, count, offsets,
                                                 aL, aR, hb, bias, out);
}

// Round 4
// 257.827 us; speedup vs baseline: 1.0503x; 1.0503x over previous
//
#include <hip/hip_runtime.h>
#include <cstdint>

#define N_NODES 50000
#define N_EDGES 800000
#define F_IN    128
#define N_HEADS 4
#define HEAD_DIM 32
#define F_OUT   128
#define NBLK_SCAN 196                     // ceil(50000/256)
#define PREP_GRID 391

typedef unsigned int uint32;
typedef unsigned short ushort;
typedef __attribute__((ext_vector_type(8))) short short8v;   // 8 bf16 in 4 VGPRs
typedef __attribute__((ext_vector_type(4))) float float4v;

__device__ __forceinline__ ushort f2bf(float f) {
    uint32 u = __float_as_uint(f);
    return (ushort)((u + 0x7FFFu + ((u >> 16) & 1u)) >> 16);   // RNE
}

// alpha storage permutation: head h -> slot {0->0, 1->2, 2->1, 3->3}
// so lane group l>>5 = g reads (head g, head g+2) as one float2 at slot 2g.

// ---------------------------------------------------------------------------
// K0: prep — WT_hi/WT_lo (bf16 split of W, transposed to [n][k]) + in-degree
// histogram.
// ---------------------------------------------------------------------------
__global__ __launch_bounds__(256) void k_prep(const float* __restrict__ W,
    const int* __restrict__ ei_to, ushort* __restrict__ WT_hi,
    ushort* __restrict__ WT_lo, int* __restrict__ count)
{
    const int id = blockIdx.x * 256 + threadIdx.x;
    if (id < F_IN * F_OUT) {
        const int n = id & 127, k = id >> 7;
        const float w = W[k * F_OUT + n];          // coalesced over n
        const ushort hi = f2bf(w);
        const float hif = __uint_as_float((uint32)hi << 16);
        const ushort lo = f2bf(w - hif);
        WT_hi[n * F_IN + k] = hi;
        WT_lo[n * F_IN + k] = lo;
    }
    for (int e = id; e < N_EDGES; e += PREP_GRID * 256)
        atomicAdd(&count[ei_to[e]], 1);
}

// ---------------------------------------------------------------------------
// K1: h = x @ W via split-bf16 MFMA (hi*hi + lo*hi + hi*lo ≈ fp32-exact).
// One wave per 16-row strip; no LDS, no barriers.
// hbp packed layout: hbp[row*64 + c] = (bf16 h[c]) | (bf16 h[c+64]) << 16,
// both halves produced by the same lane (C-tiles nt and nt+4) -> dword stores.
// ---------------------------------------------------------------------------
__global__ __launch_bounds__(256) void k_gemm_mfma(
    const float* __restrict__ x,
    const ushort* __restrict__ WT_hi, const ushort* __restrict__ WT_lo,
    const float* __restrict__ attl, const float* __restrict__ attr,
    uint32* __restrict__ hbp, float* __restrict__ aLp, float* __restrict__ aRp)
{
    const int lane = threadIdx.x & 63;
    const int wv   = threadIdx.x >> 6;
    const int q    = lane >> 4;
    const int c15  = lane & 15;
    const int row0 = blockIdx.x * 64 + wv * 16;
    if (row0 >= N_NODES) return;                  // wave-uniform exit

    // --- A fragments: x rows, split into bf16 hi + lo -----------------------
    const float* xrow = x + (size_t)(row0 + c15) * F_IN + q * 8;
    short8v ahi[4], alo[4];
#pragma unroll
    for (int kt = 0; kt < 4; ++kt) {
        const float4 f0 = *(const float4*)(xrow + kt * 32);
        const float4 f1 = *(const float4*)(xrow + kt * 32 + 4);
        const float fs[8] = {f0.x, f0.y, f0.z, f0.w, f1.x, f1.y, f1.z, f1.w};
#pragma unroll
        for (int j = 0; j < 8; ++j) {
            const ushort hi = f2bf(fs[j]);
            const float hif = __uint_as_float((uint32)hi << 16);
            const ushort lo = f2bf(fs[j] - hif);
            ahi[kt][j] = (short)hi;
            alo[kt][j] = (short)lo;
        }
    }

    float4v acc[8];
#pragma unroll
    for (int nt = 0; nt < 8; ++nt) {
        float4v a = {0.f, 0.f, 0.f, 0.f};
        const ushort* bh_base = WT_hi + ((nt * 16 + c15) << 7) + q * 8;
        const ushort* bl_base = WT_lo + ((nt * 16 + c15) << 7) + q * 8;
#pragma unroll
        for (int kt = 0; kt < 4; ++kt) {
            const short8v bh = *(const short8v*)(bh_base + kt * 32);
            const short8v bl = *(const short8v*)(bl_base + kt * 32);
            a = __builtin_amdgcn_mfma_f32_16x16x32_bf16(ahi[kt], bh, a, 0, 0, 0);
            a = __builtin_amdgcn_mfma_f32_16x16x32_bf16(alo[kt], bh, a, 0, 0, 0);
            a = __builtin_amdgcn_mfma_f32_16x16x32_bf16(ahi[kt], bl, a, 0, 0, 0);
        }
        acc[nt] = a;
    }

    // --- packed h store: dword = bf(dim c) | bf(dim c+64)<<16 ----------------
#pragma unroll
    for (int nt = 0; nt < 4; ++nt) {
#pragma unroll
        for (int r = 0; r < 4; ++r) {
            const uint32 d = (uint32)f2bf(acc[nt][r]) | ((uint32)f2bf(acc[nt + 4][r]) << 16);
            hbp[(size_t)(row0 + q * 4 + r) * 64 + nt * 16 + c15] = d;
        }
    }

    // --- alphas from exact fp32 accumulators --------------------------------
    float aLacc[4][4] = {{0.f}}, aRacc[4][4] = {{0.f}};
#pragma unroll
    for (int nt = 0; nt < 8; ++nt) {
        const float alv = attl[nt * 16 + c15];
        const float arv = attr[nt * 16 + c15];
        const int hh = nt >> 1;
#pragma unroll
        for (int r = 0; r < 4; ++r) {
            aLacc[r][hh] = fmaf(acc[nt][r], alv, aLacc[r][hh]);
            aRacc[r][hh] = fmaf(acc[nt][r], arv, aRacc[r][hh]);
        }
    }
#pragma unroll
    for (int r = 0; r < 4; ++r) {
#pragma unroll
        for (int hh = 0; hh < 4; ++hh) {
            float vl = aLacc[r][hh], vr = aRacc[r][hh];
#pragma unroll
            for (int d = 1; d < 16; d <<= 1) {
                vl += __shfl_xor(vl, d);
                vr += __shfl_xor(vr, d);
            }
            if (c15 == hh) {
                const int row = row0 + q * 4 + r;
                const int pos = (hh & 1) * 2 + (hh >> 1);   // permuted slot
                aLp[row * N_HEADS + pos] = vl;
                aRp[row * N_HEADS + pos] = vr;
            }
        }
    }
}

// ---------------------------------------------------------------------------
// 2-level exclusive scan over 50000 counts
// ---------------------------------------------------------------------------
__device__ __forceinline__ int block_scan_excl_256(int v, int* p_total)
{
    const int t = threadIdx.x, lane = t & 63, wv = t >> 6;
    int incl = v;
#pragma unroll
    for (int d = 1; d < 64; d <<= 1) {
        int u = __shfl_up(incl, d);
        if (lane >= d) incl += u;
    }
    __shared__ int wsum[4];
    if (lane == 63) wsum[wv] = incl;
    __syncthreads();
    int woff = 0;
#pragma unroll
    for (int j = 0; j < 4; ++j) {
        int s = wsum[j];
        if (j < wv) woff += s;
    }
    if (p_total) *p_total = wsum[0] + wsum[1] + wsum[2] + wsum[3];
    __syncthreads();
    return woff + incl - v;
}

__global__ __launch_bounds__(256) void k_scan1(const int* __restrict__ count,
                                               int* __restrict__ scanned,
                                               int* __restrict__ blocksum)
{
    int i = blockIdx.x * 256 + threadIdx.x;
    int v = (i < N_NODES) ? count[i] : 0;
    int tot;
    int ex = block_scan_excl_256(v, &tot);
    if (i < N_NODES) scanned[i] = ex;
    if (threadIdx.x == 0) blocksum[blockIdx.x] = tot;
}

__global__ __launch_bounds__(256) void k_scan2(const int* __restrict__ blocksum,
                                               int* __restrict__ blockoff)
{
    int t = threadIdx.x;
    int v = (t < NBLK_SCAN) ? blocksum[t] : 0;
    int ex = block_scan_excl_256(v, nullptr);
    if (t < NBLK_SCAN) blockoff[t] = ex;
}

__global__ __launch_bounds__(256) void k_scan3(const int* __restrict__ scanned,
                                               const int* __restrict__ blockoff,
                                               int* __restrict__ offsets,
                                               int* __restrict__ cursor)
{
    int i = blockIdx.x * 256 + threadIdx.x;
    if (i < N_NODES) {
        int off = scanned[i] + blockoff[blockIdx.x];
        offsets[i] = off;
        cursor[i]  = off;
    }
}

// ---------------------------------------------------------------------------
// K4: scatter edge source ids into destination-sorted CSR order.
// ---------------------------------------------------------------------------
__global__ __launch_bounds__(256) void k_scatter(const int* __restrict__ ei,
    int* __restrict__ cursor, int* __restrict__ rec_from)
{
    int e = blockIdx.x * 256 + threadIdx.x;
    if (e >= N_EDGES) return;
    int from = ei[e], to = ei[N_EDGES + e];
    int pos = atomicAdd(&cursor[to], 1);
    rec_from[pos] = from;
}

// ---------------------------------------------------------------------------
// K5: pull aggregation. Wave per node; lane owns dims (l, l+64) via packed hbp.
// Unroll-by-4: 4 independent 256-B gathers in flight per wave.
// ---------------------------------------------------------------------------
__global__ __launch_bounds__(256) void k_agg(const int* __restrict__ rec_from,
    const int* __restrict__ count, const int* __restrict__ offsets,
    const float* __restrict__ aLp, const float* __restrict__ aRp,
    const uint32* __restrict__ hbp,
    const float* __restrict__ bias, float* __restrict__ out)
{
    const int lane = threadIdx.x & 63;
    const int n = blockIdx.x * 4 + (threadIdx.x >> 6);
    if (n >= N_NODES) return;
    const int cnt  = count[n];
    const int off  = offsets[n];
    const int hsel = (lane >> 5) * 2;   // alpha slot for (head l>>5, head l>>5+2)
    const float2 arv = *(const float2*)&aRp[n * N_HEADS + hsel];
    float ax = 0.f, ay = 0.f, ds0 = 0.f, ds1 = 0.f;

    for (int base = 0; base < cnt; base += 64) {
        const int m = min(64, cnt - base);
        int vf = 0;
        if (lane < m) vf = rec_from[off + base + lane];   // coalesced preload
        int i = 0;
        for (; i + 4 <= m; i += 4) {
            const int f0 = __shfl(vf, i), f1 = __shfl(vf, i + 1);
            const int f2i = __shfl(vf, i + 2), f3 = __shfl(vf, i + 3);
            const uint32 h0 = hbp[(size_t)f0 * 64 + lane];
            const uint32 h1 = hbp[(size_t)f1 * 64 + lane];
            const uint32 h2 = hbp[(size_t)f2i * 64 + lane];
            const uint32 h3 = hbp[(size_t)f3 * 64 + lane];
            const float2 a0 = *(const float2*)&aLp[f0 * N_HEADS + hsel];
            const float2 a1 = *(const float2*)&aLp[f1 * N_HEADS + hsel];
            const float2 a2 = *(const float2*)&aLp[f2i * N_HEADS + hsel];
            const float2 a3 = *(const float2*)&aLp[f3 * N_HEADS + hsel];
#define EDGE(hv, af)                                                         \
            {                                                                \
                float e0 = af.x + arv.x; e0 = (e0 > 0.f) ? e0 : 0.2f * e0;   \
                float e1 = af.y + arv.y; e1 = (e1 > 0.f) ? e1 : 0.2f * e1;   \
                e0 = __expf(e0); e1 = __expf(e1);                            \
                ax = fmaf(e0, __uint_as_float((hv) << 16), ax);              \
                ay = fmaf(e1, __uint_as_float((hv) & 0xFFFF0000u), ay);      \
                ds0 += e0; ds1 += e1;                                        \
            }
            EDGE(h0, a0) EDGE(h1, a1) EDGE(h2, a2) EDGE(h3, a3)
        }
        for (; i < m; ++i) {
            const int fi = __shfl(vf, i);
            const uint32 hv = hbp[(size_t)fi * 64 + lane];
            const float2 af = *(const float2*)&aLp[fi * N_HEADS + hsel];
            EDGE(hv, af)
        }
#undef EDGE
    }
    const float inv0 = 1.0f / (ds0 + 1e-9f);
    const float inv1 = 1.0f / (ds1 + 1e-9f);
    out[n * F_OUT + lane]      = ax * inv0 + bias[lane];
    out[n * F_OUT + 64 + lane] = ay * inv1 + bias[64 + lane];
}

// ---------------------------------------------------------------------------
extern "C" void kernel_launch(void* const* d_in, const int* in_sizes, int n_in,
                              void* d_out, int out_size, void* d_ws, size_t ws_size,
                              hipStream_t stream)
{
    const float* x    = (const float*)d_in[0];
    const int*   ei   = (const int*)d_in[1];
    const float* W    = (const float*)d_in[2];
    const float* attl = (const float*)d_in[3];
    const float* attr = (const float*)d_in[4];
    const float* bias = (const float*)d_in[5];
    float* out = (float*)d_out;

    char* p = (char*)d_ws;
    auto carve = [&](size_t bytes) -> char* {
        char* q = p;
        p += (bytes + 255) & ~size_t(255);
        return q;
    };
    uint32* hbp      = (uint32*)carve((size_t)N_NODES * 64 * 4);     // 12.8 MB
    ushort* WT_hi    = (ushort*)carve((size_t)F_IN * F_OUT * 2);     // 32 KB
    ushort* WT_lo    = (ushort*)carve((size_t)F_IN * F_OUT * 2);     // 32 KB
    float*  aLp      = (float*)carve((size_t)N_NODES * N_HEADS * 4);
    float*  aRp      = (float*)carve((size_t)N_NODES * N_HEADS * 4);
    int*    count    = (int*)carve((size_t)N_NODES * 4);
    int*    scanned  = (int*)carve((size_t)N_NODES * 4);
    int*    offsets  = (int*)carve((size_t)N_NODES * 4);
    int*    cursor   = (int*)carve((size_t)N_NODES * 4);
    int*    blocksum = (int*)carve(256 * 4);
    int*    blockoff = (int*)carve(256 * 4);
    int*    rec_from = (int*)carve((size_t)N_EDGES * 4);             // 3.2 MB

    hipMemsetAsync(count, 0, N_NODES * 4, stream);

    k_prep<<<PREP_GRID, 256, 0, stream>>>(W, ei + N_EDGES, WT_hi, WT_lo, count);
    k_gemm_mfma<<<(N_NODES + 63) / 64, 256, 0, stream>>>(x, WT_hi, WT_lo,
                                                         attl, attr, hbp, aLp, aRp);
    k_scan1<<<NBLK_SCAN, 256, 0, stream>>>(count, scanned, blocksum);
    k_scan2<<<1, 256, 0, stream>>>(blocksum, blockoff);
    k_scan3<<<NBLK_SCAN, 256, 0, stream>>>(scanned, blockoff, offsets, cursor);
    k_scatter<<<(N_EDGES + 255) / 256, 256, 0, stream>>>(ei, cursor, rec_from);
    k_agg<<<(N_NODES + 3) / 4, 256, 0, stream>>>(rec_from, count, offsets,
                                                 aLp, aRp, hbp, bias, out);
}

// Round 5
// 193.042 us; speedup vs baseline: 1.4028x; 1.3356x over previous
//
#include <hip/hip_runtime.h>
#include <cstdint>

#define N_NODES 50000
#define N_EDGES 800000
#define F_IN    128
#define N_HEADS 4
#define HEAD_DIM 32
#define F_OUT   128

#define NBUCK   196                 // ceil(50000/256) coarse buckets (to>>8)
#define KA_GRID 256                 // binning blocks (each owns private regions)
#define EPB     (N_EDGES / KA_GRID) // 3125 edges per binning block
#define CAPA    64                  // slots per (bucket, block); avg fill ~16
#define STAGE_CAP 6144              // LDS staging entries in k_build (avg ~4082)

typedef unsigned int uint32;
typedef unsigned short ushort;
typedef __attribute__((ext_vector_type(8))) short short8v;   // 8 bf16 in 4 VGPRs
typedef __attribute__((ext_vector_type(4))) float float4v;

__device__ __forceinline__ ushort f2bf(float f) {
    uint32 u = __float_as_uint(f);
    return (ushort)((u + 0x7FFFu + ((u >> 16) & 1u)) >> 16);   // RNE
}

// ---------------------------------------------------------------------------
// block-wide exclusive scan over 256 ints (4 waves)
// ---------------------------------------------------------------------------
__device__ __forceinline__ int block_scan_excl_256(int v, int* p_total)
{
    const int t = threadIdx.x, lane = t & 63, wv = t >> 6;
    int incl = v;
#pragma unroll
    for (int d = 1; d < 64; d <<= 1) {
        int u = __shfl_up(incl, d);
        if (lane >= d) incl += u;
    }
    __shared__ int wsum[4];
    if (lane == 63) wsum[wv] = incl;
    __syncthreads();
    int woff = 0;
#pragma unroll
    for (int j = 0; j < 4; ++j) {
        int s = wsum[j];
        if (j < wv) woff += s;
    }
    if (p_total) *p_total = wsum[0] + wsum[1] + wsum[2] + wsum[3];
    __syncthreads();
    return woff + incl - v;
}

// ---------------------------------------------------------------------------
// kA: bin edges into per-block private bucket regions (single-writer ->
// stores merge in the owning XCD's L2 -> full-line writebacks).
// Also performs the W bf16 hi/lo split (blocks 0..63).
// ---------------------------------------------------------------------------
__global__ __launch_bounds__(256) void k_bin(const int* __restrict__ ei,
    const float* __restrict__ W, ushort* __restrict__ WT_hi,
    ushort* __restrict__ WT_lo, uint2* __restrict__ priv, int* __restrict__ cnts)
{
    const int sb = blockIdx.x, t = threadIdx.x;

    const int id = sb * 256 + t;                 // W split: first 64 blocks
    if (id < F_IN * F_OUT) {
        const int n = id & 127, k = id >> 7;
        const float w = W[k * F_OUT + n];        // coalesced over n
        const ushort hi = f2bf(w);
        const float hif = __uint_as_float((uint32)hi << 16);
        WT_hi[n * F_IN + k] = hi;
        WT_lo[n * F_IN + k] = f2bf(w - hif);
    }

    __shared__ int cur[NBUCK];
    if (t < NBUCK) cur[t] = 0;
    __syncthreads();

    const int e0 = sb * EPB;
    for (int i = t; i < EPB; i += 256) {
        const int from = ei[e0 + i];
        const int to   = ei[N_EDGES + e0 + i];
        const int b = to >> 8;
        const int slot = atomicAdd(&cur[b], 1);
        if (slot < CAPA)                          // 12-sigma guard, never fires
            priv[((size_t)b * KA_GRID + sb) * CAPA + slot] =
                make_uint2((uint32)from, (uint32)to);
    }
    __syncthreads();
    if (t < NBUCK) cnts[t * KA_GRID + sb] = min(cur[t], CAPA);
}

// ---------------------------------------------------------------------------
// kB0: exclusive scan of bucket totals -> bucket_base
// ---------------------------------------------------------------------------
__global__ __launch_bounds__(256) void k_bucket_base(const int* __restrict__ cnts,
    int* __restrict__ bucket_base)
{
    const int t = threadIdx.x;
    int s = 0;
    if (t < NBUCK)
        for (int sb = 0; sb < KA_GRID; ++sb) s += cnts[t * KA_GRID + sb];
    int tot;
    const int ex = block_scan_excl_256(s, &tot);
    if (t < NBUCK) bucket_base[t] = ex;
}

// ---------------------------------------------------------------------------
// kB: one block per bucket. Stage bucket edges in LDS, LDS histogram + scan
// -> count/offsets (coalesced) and CSR scatter confined to the bucket's own
// range (single-writer -> merged writebacks).
// ---------------------------------------------------------------------------
__global__ __launch_bounds__(256) void k_build(const uint2* __restrict__ priv,
    const int* __restrict__ cnts, const int* __restrict__ bucket_base,
    int* __restrict__ count, int* __restrict__ offsets, int* __restrict__ rec_from)
{
    __shared__ uint2 stage[STAGE_CAP];
    __shared__ int hist[256];
    __shared__ int curn[256];
    const int b = blockIdx.x, t = threadIdx.x;

    const int ct = cnts[b * KA_GRID + t];         // coalesced (KA_GRID==256)
    int total;
    const int so = block_scan_excl_256(ct, &total);

    const uint2* seg = priv + ((size_t)b * KA_GRID + t) * CAPA;
    if (so + ct <= STAGE_CAP)
        for (int i = 0; i < ct; ++i) stage[so + i] = seg[i];
    hist[t] = 0;
    __syncthreads();

    const int S = min(total, STAGE_CAP);
    for (int i = t; i < S; i += 256) atomicAdd(&hist[stage[i].y & 255], 1);
    __syncthreads();

    const int hv = hist[t];
    int tot2;
    const int lo = block_scan_excl_256(hv, &tot2);
    const int base = bucket_base[b];
    const int n = b * 256 + t;
    if (n < N_NODES) {
        count[n]   = hv;
        offsets[n] = base + lo;
    }
    curn[t] = lo;
    __syncthreads();

    for (int i = t; i < S; i += 256) {
        const uint2 e = stage[i];
        const int pos = atomicAdd(&curn[e.y & 255], 1);
        rec_from[base + pos] = (int)e.x;
    }
}

// ---------------------------------------------------------------------------
// K1: h = x @ W via split-bf16 MFMA (hi*hi + lo*hi + hi*lo ≈ fp32-exact).
// One wave per 16-row strip; no LDS, no barriers.
// hbp packed layout: hbp[row*64 + c] = (bf16 h[c]) | (bf16 h[c+64]) << 16.
// ---------------------------------------------------------------------------
__global__ __launch_bounds__(256) void k_gemm_mfma(
    const float* __restrict__ x,
    const ushort* __restrict__ WT_hi, const ushort* __restrict__ WT_lo,
    const float* __restrict__ attl, const float* __restrict__ attr,
    uint32* __restrict__ hbp, float* __restrict__ aLp, float* __restrict__ aRp)
{
    const int lane = threadIdx.x & 63;
    const int wv   = threadIdx.x >> 6;
    const int q    = lane >> 4;
    const int c15  = lane & 15;
    const int row0 = blockIdx.x * 64 + wv * 16;
    if (row0 >= N_NODES) return;                  // wave-uniform exit

    const float* xrow = x + (size_t)(row0 + c15) * F_IN + q * 8;
    short8v ahi[4], alo[4];
#pragma unroll
    for (int kt = 0; kt < 4; ++kt) {
        const float4 f0 = *(const float4*)(xrow + kt * 32);
        const float4 f1 = *(const float4*)(xrow + kt * 32 + 4);
        const float fs[8] = {f0.x, f0.y, f0.z, f0.w, f1.x, f1.y, f1.z, f1.w};
#pragma unroll
        for (int j = 0; j < 8; ++j) {
            const ushort hi = f2bf(fs[j]);
            const float hif = __uint_as_float((uint32)hi << 16);
            ahi[kt][j] = (short)hi;
            alo[kt][j] = (short)f2bf(fs[j] - hif);
        }
    }

    float4v acc[8];
#pragma unroll
    for (int nt = 0; nt < 8; ++nt) {
        float4v a = {0.f, 0.f, 0.f, 0.f};
        const ushort* bh_base = WT_hi + ((nt * 16 + c15) << 7) + q * 8;
        const ushort* bl_base = WT_lo + ((nt * 16 + c15) << 7) + q * 8;
#pragma unroll
        for (int kt = 0; kt < 4; ++kt) {
            const short8v bh = *(const short8v*)(bh_base + kt * 32);
            const short8v bl = *(const short8v*)(bl_base + kt * 32);
            a = __builtin_amdgcn_mfma_f32_16x16x32_bf16(ahi[kt], bh, a, 0, 0, 0);
            a = __builtin_amdgcn_mfma_f32_16x16x32_bf16(alo[kt], bh, a, 0, 0, 0);
            a = __builtin_amdgcn_mfma_f32_16x16x32_bf16(ahi[kt], bl, a, 0, 0, 0);
        }
        acc[nt] = a;
    }

#pragma unroll
    for (int nt = 0; nt < 4; ++nt) {
#pragma unroll
        for (int r = 0; r < 4; ++r) {
            const uint32 d = (uint32)f2bf(acc[nt][r]) | ((uint32)f2bf(acc[nt + 4][r]) << 16);
            hbp[(size_t)(row0 + q * 4 + r) * 64 + nt * 16 + c15] = d;
        }
    }

    float aLacc[4][4] = {{0.f}}, aRacc[4][4] = {{0.f}};
#pragma unroll
    for (int nt = 0; nt < 8; ++nt) {
        const float alv = attl[nt * 16 + c15];
        const float arv = attr[nt * 16 + c15];
        const int hh = nt >> 1;
#pragma unroll
        for (int r = 0; r < 4; ++r) {
            aLacc[r][hh] = fmaf(acc[nt][r], alv, aLacc[r][hh]);
            aRacc[r][hh] = fmaf(acc[nt][r], arv, aRacc[r][hh]);
        }
    }
#pragma unroll
    for (int r = 0; r < 4; ++r) {
#pragma unroll
        for (int hh = 0; hh < 4; ++hh) {
            float vl = aLacc[r][hh], vr = aRacc[r][hh];
#pragma unroll
            for (int d = 1; d < 16; d <<= 1) {
                vl += __shfl_xor(vl, d);
                vr += __shfl_xor(vr, d);
            }
            if (c15 == hh) {
                const int row = row0 + q * 4 + r;
                const int pos = (hh & 1) * 2 + (hh >> 1);   // permuted slot
                aLp[row * N_HEADS + pos] = vl;
                aRp[row * N_HEADS + pos] = vr;
            }
        }
    }
}

// ---------------------------------------------------------------------------
// K5: pull aggregation. Wave per node; lane owns dims (l, l+64) via packed hbp.
// Unroll-by-4: 4 independent 256-B gathers in flight per wave.
// Softmax max-shift cancels in ex/sum(ex); att <= ~10 so no fp32 overflow.
// ---------------------------------------------------------------------------
__global__ __launch_bounds__(256) void k_agg(const int* __restrict__ rec_from,
    const int* __restrict__ count, const int* __restrict__ offsets,
    const float* __restrict__ aLp, const float* __restrict__ aRp,
    const uint32* __restrict__ hbp,
    const float* __restrict__ bias, float* __restrict__ out)
{
    const int lane = threadIdx.x & 63;
    const int n = blockIdx.x * 4 + (threadIdx.x >> 6);
    if (n >= N_NODES) return;
    const int cnt  = count[n];
    const int off  = offsets[n];
    const int hsel = (lane >> 5) * 2;   // alpha slot for (head l>>5, head l>>5+2)
    const float2 arv = *(const float2*)&aRp[n * N_HEADS + hsel];
    float ax = 0.f, ay = 0.f, ds0 = 0.f, ds1 = 0.f;

    for (int base = 0; base < cnt; base += 64) {
        const int m = min(64, cnt - base);
        int vf = 0;
        if (lane < m) vf = rec_from[off + base + lane];   // coalesced preload
        int i = 0;
        for (; i + 4 <= m; i += 4) {
            const int f0 = __shfl(vf, i), f1 = __shfl(vf, i + 1);
            const int f2i = __shfl(vf, i + 2), f3 = __shfl(vf, i + 3);
            const uint32 h0 = hbp[(size_t)f0 * 64 + lane];
            const uint32 h1 = hbp[(size_t)f1 * 64 + lane];
            const uint32 h2 = hbp[(size_t)f2i * 64 + lane];
            const uint32 h3 = hbp[(size_t)f3 * 64 + lane];
            const float2 a0 = *(const float2*)&aLp[f0 * N_HEADS + hsel];
            const float2 a1 = *(const float2*)&aLp[f1 * N_HEADS + hsel];
            const float2 a2 = *(const float2*)&aLp[f2i * N_HEADS + hsel];
            const float2 a3 = *(const float2*)&aLp[f3 * N_HEADS + hsel];
#define EDGE(hv, af)                                                         \
            {                                                                \
                float e0 = af.x + arv.x; e0 = (e0 > 0.f) ? e0 : 0.2f * e0;   \
                float e1 = af.y + arv.y; e1 = (e1 > 0.f) ? e1 : 0.2f * e1;   \
                e0 = __expf(e0); e1 = __expf(e1);                            \
                ax = fmaf(e0, __uint_as_float((hv) << 16), ax);              \
                ay = fmaf(e1, __uint_as_float((hv) & 0xFFFF0000u), ay);      \
                ds0 += e0; ds1 += e1;                                        \
            }
            EDGE(h0, a0) EDGE(h1, a1) EDGE(h2, a2) EDGE(h3, a3)
        }
        for (; i < m; ++i) {
            const int fi = __shfl(vf, i);
            const uint32 hv = hbp[(size_t)fi * 64 + lane];
            const float2 af = *(const float2*)&aLp[fi * N_HEADS + hsel];
            EDGE(hv, af)
        }
#undef EDGE
    }
    const float inv0 = 1.0f / (ds0 + 1e-9f);
    const float inv1 = 1.0f / (ds1 + 1e-9f);
    out[n * F_OUT + lane]      = ax * inv0 + bias[lane];
    out[n * F_OUT + 64 + lane] = ay * inv1 + bias[64 + lane];
}

// ---------------------------------------------------------------------------
extern "C" void kernel_launch(void* const* d_in, const int* in_sizes, int n_in,
                              void* d_out, int out_size, void* d_ws, size_t ws_size,
                              hipStream_t stream)
{
    const float* x    = (const float*)d_in[0];
    const int*   ei   = (const int*)d_in[1];
    const float* W    = (const float*)d_in[2];
    const float* attl = (const float*)d_in[3];
    const float* attr = (const float*)d_in[4];
    const float* bias = (const float*)d_in[5];
    float* out = (float*)d_out;

    char* p = (char*)d_ws;
    auto carve = [&](size_t bytes) -> char* {
        char* q = p;
        p += (bytes + 255) & ~size_t(255);
        return q;
    };
    uint32* hbp       = (uint32*)carve((size_t)N_NODES * 64 * 4);          // 12.8 MB
    uint2*  priv      = (uint2*)carve((size_t)NBUCK * KA_GRID * CAPA * 8); // 25.7 MB
    int*    rec_from  = (int*)carve((size_t)N_EDGES * 4);                  // 3.2 MB
    ushort* WT_hi     = (ushort*)carve((size_t)F_IN * F_OUT * 2);
    ushort* WT_lo     = (ushort*)carve((size_t)F_IN * F_OUT * 2);
    float*  aLp       = (float*)carve((size_t)N_NODES * N_HEADS * 4);
    float*  aRp       = (float*)carve((size_t)N_NODES * N_HEADS * 4);
    int*    cnts      = (int*)carve((size_t)NBUCK * KA_GRID * 4);          // 200 KB
    int*    bucket_base = (int*)carve(NBUCK * 4);
    int*    count     = (int*)carve((size_t)N_NODES * 4);
    int*    offsets   = (int*)carve((size_t)N_NODES * 4);

    k_bin<<<KA_GRID, 256, 0, stream>>>(ei, W, WT_hi, WT_lo, priv, cnts);
    k_bucket_base<<<1, 256, 0, stream>>>(cnts, bucket_base);
    k_build<<<NBUCK, 256, 0, stream>>>(priv, cnts, bucket_base,
                                       count, offsets, rec_from);
    k_gemm_mfma<<<(N_NODES + 63) / 64, 256, 0, stream>>>(x, WT_hi, WT_lo,
                                                         attl, attr, hbp, aLp, aRp);
    k_agg<<<(N_NODES + 3) / 4, 256, 0, stream>>>(rec_from, count, offsets,
                                                 aLp, aRp, hbp, bias, out);
}

// Round 6
// 181.275 us; speedup vs baseline: 1.4939x; 1.0649x over previous
//
#include <hip/hip_runtime.h>
#include <cstdint>

#define N_NODES 50000
#define N_EDGES 800000
#define F_IN    128
#define N_HEADS 4
#define HEAD_DIM 32
#define F_OUT   128

#define NBUCK   196                 // ceil(50000/256) coarse buckets (to>>8)
#define KA_GRID 256                 // binning blocks (each owns private regions)
#define EPB     (N_EDGES / KA_GRID) // 3125 edges per binning block
#define CAPA    64                  // slots per (bucket, block); avg fill ~16
#define STAGE_CAP 6144              // LDS staging entries in k_build (avg ~4082)

typedef unsigned int uint32;
typedef unsigned short ushort;
typedef __attribute__((ext_vector_type(8))) short short8v;   // 8 bf16 in 4 VGPRs
typedef __attribute__((ext_vector_type(4))) float float4v;

__device__ __forceinline__ ushort f2bf(float f) {
    uint32 u = __float_as_uint(f);
    return (ushort)((u + 0x7FFFu + ((u >> 16) & 1u)) >> 16);   // RNE
}

// ---------------------------------------------------------------------------
// block-wide exclusive scan over 256 ints (4 waves)
// ---------------------------------------------------------------------------
__device__ __forceinline__ int block_scan_excl_256(int v, int* p_total)
{
    const int t = threadIdx.x, lane = t & 63, wv = t >> 6;
    int incl = v;
#pragma unroll
    for (int d = 1; d < 64; d <<= 1) {
        int u = __shfl_up(incl, d);
        if (lane >= d) incl += u;
    }
    __shared__ int wsum[4];
    if (lane == 63) wsum[wv] = incl;
    __syncthreads();
    int woff = 0;
#pragma unroll
    for (int j = 0; j < 4; ++j) {
        int s = wsum[j];
        if (j < wv) woff += s;
    }
    if (p_total) *p_total = wsum[0] + wsum[1] + wsum[2] + wsum[3];
    __syncthreads();
    return woff + incl - v;
}

// ---------------------------------------------------------------------------
// kA: bin edges into per-block private bucket regions (single-writer ->
// stores merge in the owning XCD's L2). Also W bf16 hi/lo split.
// ---------------------------------------------------------------------------
__global__ __launch_bounds__(256) void k_bin(const int* __restrict__ ei,
    const float* __restrict__ W, ushort* __restrict__ WT_hi,
    ushort* __restrict__ WT_lo, uint2* __restrict__ priv, int* __restrict__ cnts)
{
    const int sb = blockIdx.x, t = threadIdx.x;

    const int id = sb * 256 + t;                 // W split: first 64 blocks
    if (id < F_IN * F_OUT) {
        const int n = id & 127, k = id >> 7;
        const float w = W[k * F_OUT + n];        // coalesced over n
        const ushort hi = f2bf(w);
        const float hif = __uint_as_float((uint32)hi << 16);
        WT_hi[n * F_IN + k] = hi;
        WT_lo[n * F_IN + k] = f2bf(w - hif);
    }

    __shared__ int cur[NBUCK];
    if (t < NBUCK) cur[t] = 0;
    __syncthreads();

    const int e0 = sb * EPB;
    for (int i = t; i < EPB; i += 256) {
        const int from = ei[e0 + i];
        const int to   = ei[N_EDGES + e0 + i];
        const int b = to >> 8;
        const int slot = atomicAdd(&cur[b], 1);
        if (slot < CAPA)                          // 12-sigma guard, never fires
            priv[((size_t)b * KA_GRID + sb) * CAPA + slot] =
                make_uint2((uint32)from, (uint32)to);
    }
    __syncthreads();
    if (t < NBUCK) cnts[t * KA_GRID + sb] = min(cur[t], CAPA);
}

// ---------------------------------------------------------------------------
// kB-sum: one block per bucket, coalesced load of its 256 sub-counts,
// block-reduce -> bsum[b]. (Replaces the single-block serial-load whale.)
// ---------------------------------------------------------------------------
__global__ __launch_bounds__(256) void k_bsum(const int* __restrict__ cnts,
                                              int* __restrict__ bsum)
{
    const int b = blockIdx.x, t = threadIdx.x;
    int v = cnts[b * KA_GRID + t];
#pragma unroll
    for (int d = 32; d; d >>= 1) v += __shfl_xor(v, d);
    __shared__ int ws[4];
    if ((t & 63) == 0) ws[t >> 6] = v;
    __syncthreads();
    if (t == 0) bsum[b] = ws[0] + ws[1] + ws[2] + ws[3];
}

// ---------------------------------------------------------------------------
// kB0: exclusive scan of 196 bucket totals -> bucket_base
// ---------------------------------------------------------------------------
__global__ __launch_bounds__(256) void k_scan_base(const int* __restrict__ bsum,
    int* __restrict__ bucket_base)
{
    const int t = threadIdx.x;
    int v = (t < NBUCK) ? bsum[t] : 0;
    const int ex = block_scan_excl_256(v, nullptr);
    if (t < NBUCK) bucket_base[t] = ex;
}

// ---------------------------------------------------------------------------
// kB: one block per bucket. Stage bucket edges in LDS, LDS histogram + scan
// -> count/offsets (coalesced) and CSR scatter confined to the bucket's own
// range (single-writer -> merged writebacks).
// ---------------------------------------------------------------------------
__global__ __launch_bounds__(256) void k_build(const uint2* __restrict__ priv,
    const int* __restrict__ cnts, const int* __restrict__ bucket_base,
    int* __restrict__ count, int* __restrict__ offsets, int* __restrict__ rec_from)
{
    __shared__ uint2 stage[STAGE_CAP];
    __shared__ int hist[256];
    __shared__ int curn[256];
    const int b = blockIdx.x, t = threadIdx.x;

    const int ct = cnts[b * KA_GRID + t];         // coalesced (KA_GRID==256)
    int total;
    const int so = block_scan_excl_256(ct, &total);

    const uint2* seg = priv + ((size_t)b * KA_GRID + t) * CAPA;
    if (so + ct <= STAGE_CAP)
        for (int i = 0; i < ct; ++i) stage[so + i] = seg[i];
    hist[t] = 0;
    __syncthreads();

    const int S = min(total, STAGE_CAP);
    for (int i = t; i < S; i += 256) atomicAdd(&hist[stage[i].y & 255], 1);
    __syncthreads();

    const int hv = hist[t];
    int tot2;
    const int lo = block_scan_excl_256(hv, &tot2);
    const int base = bucket_base[b];
    const int n = b * 256 + t;
    if (n < N_NODES) {
        count[n]   = hv;
        offsets[n] = base + lo;
    }
    curn[t] = lo;
    __syncthreads();

    for (int i = t; i < S; i += 256) {
        const uint2 e = stage[i];
        const int pos = atomicAdd(&curn[e.y & 255], 1);
        rec_from[base + pos] = (int)e.x;
    }
}

// ---------------------------------------------------------------------------
// K1: h = x @ W via split-bf16 MFMA (hi*hi + lo*hi + hi*lo ≈ fp32-exact).
// One wave per 16-row strip; no LDS, no barriers.
// hbp packed layout: hbp[row*64 + c] = (bf16 h[c]) | (bf16 h[c+64]) << 16.
// ---------------------------------------------------------------------------
__global__ __launch_bounds__(256) void k_gemm_mfma(
    const float* __restrict__ x,
    const ushort* __restrict__ WT_hi, const ushort* __restrict__ WT_lo,
    const float* __restrict__ attl, const float* __restrict__ attr,
    uint32* __restrict__ hbp, float* __restrict__ aLp, float* __restrict__ aRp)
{
    const int lane = threadIdx.x & 63;
    const int wv   = threadIdx.x >> 6;
    const int q    = lane >> 4;
    const int c15  = lane & 15;
    const int row0 = blockIdx.x * 64 + wv * 16;
    if (row0 >= N_NODES) return;                  // wave-uniform exit

    const float* xrow = x + (size_t)(row0 + c15) * F_IN + q * 8;
    short8v ahi[4], alo[4];
#pragma unroll
    for (int kt = 0; kt < 4; ++kt) {
        const float4 f0 = *(const float4*)(xrow + kt * 32);
        const float4 f1 = *(const float4*)(xrow + kt * 32 + 4);
        const float fs[8] = {f0.x, f0.y, f0.z, f0.w, f1.x, f1.y, f1.z, f1.w};
#pragma unroll
        for (int j = 0; j < 8; ++j) {
            const ushort hi = f2bf(fs[j]);
            const float hif = __uint_as_float((uint32)hi << 16);
            ahi[kt][j] = (short)hi;
            alo[kt][j] = (short)f2bf(fs[j] - hif);
        }
    }

    float4v acc[8];
#pragma unroll
    for (int nt = 0; nt < 8; ++nt) {
        float4v a = {0.f, 0.f, 0.f, 0.f};
        const ushort* bh_base = WT_hi + ((nt * 16 + c15) << 7) + q * 8;
        const ushort* bl_base = WT_lo + ((nt * 16 + c15) << 7) + q * 8;
#pragma unroll
        for (int kt = 0; kt < 4; ++kt) {
            const short8v bh = *(const short8v*)(bh_base + kt * 32);
            const short8v bl = *(const short8v*)(bl_base + kt * 32);
            a = __builtin_amdgcn_mfma_f32_16x16x32_bf16(ahi[kt], bh, a, 0, 0, 0);
            a = __builtin_amdgcn_mfma_f32_16x16x32_bf16(alo[kt], bh, a, 0, 0, 0);
            a = __builtin_amdgcn_mfma_f32_16x16x32_bf16(ahi[kt], bl, a, 0, 0, 0);
        }
        acc[nt] = a;
    }

#pragma unroll
    for (int nt = 0; nt < 4; ++nt) {
#pragma unroll
        for (int r = 0; r < 4; ++r) {
            const uint32 d = (uint32)f2bf(acc[nt][r]) | ((uint32)f2bf(acc[nt + 4][r]) << 16);
            hbp[(size_t)(row0 + q * 4 + r) * 64 + nt * 16 + c15] = d;
        }
    }

    float aLacc[4][4] = {{0.f}}, aRacc[4][4] = {{0.f}};
#pragma unroll
    for (int nt = 0; nt < 8; ++nt) {
        const float alv = attl[nt * 16 + c15];
        const float arv = attr[nt * 16 + c15];
        const int hh = nt >> 1;
#pragma unroll
        for (int r = 0; r < 4; ++r) {
            aLacc[r][hh] = fmaf(acc[nt][r], alv, aLacc[r][hh]);
            aRacc[r][hh] = fmaf(acc[nt][r], arv, aRacc[r][hh]);
        }
    }
#pragma unroll
    for (int r = 0; r < 4; ++r) {
#pragma unroll
        for (int hh = 0; hh < 4; ++hh) {
            float vl = aLacc[r][hh], vr = aRacc[r][hh];
#pragma unroll
            for (int d = 1; d < 16; d <<= 1) {
                vl += __shfl_xor(vl, d);
                vr += __shfl_xor(vr, d);
            }
            if (c15 == hh) {
                const int row = row0 + q * 4 + r;
                const int pos = (hh & 1) * 2 + (hh >> 1);   // permuted slot
                aLp[row * N_HEADS + pos] = vl;
                aRp[row * N_HEADS + pos] = vr;
            }
        }
    }
}

// ---------------------------------------------------------------------------
// K5: pull aggregation. Wave per node; lane owns dims (l, l+64) via packed hbp.
// Half-wave exp dedup: during preload, lane l computes the 2 exps for edge
// (l&31) at its own head-pair; consumers shfl (f, e0, e1) from lane gsel|i.
// Exp work drops 32x; shfl rides the LDS pipe. Numerics identical.
// ---------------------------------------------------------------------------
__global__ __launch_bounds__(256) void k_agg(const int* __restrict__ rec_from,
    const int* __restrict__ count, const int* __restrict__ offsets,
    const float* __restrict__ aLp, const float* __restrict__ aRp,
    const uint32* __restrict__ hbp,
    const float* __restrict__ bias, float* __restrict__ out)
{
    const int lane = threadIdx.x & 63;
    const int n = blockIdx.x * 4 + (threadIdx.x >> 6);
    if (n >= N_NODES) return;
    const int cnt  = count[n];
    const int off  = offsets[n];
    const int hsel = (lane >> 5) * 2;   // alpha slot pair for this half-wave
    const int l31  = lane & 31;
    const int gsel = lane & 32;
    const float2 arv = *(const float2*)&aRp[n * N_HEADS + hsel];
    float ax = 0.f, ay = 0.f, ds0 = 0.f, ds1 = 0.f;

    for (int base = 0; base < cnt; base += 32) {
        const int m = min(32, cnt - base);
        int vf = 0;
        float e0p = 0.f, e1p = 0.f;
        if (l31 < m) {
            vf = rec_from[off + base + l31];                  // coalesced
            const float2 af = *(const float2*)&aLp[vf * N_HEADS + hsel];
            float t0 = af.x + arv.x; t0 = (t0 > 0.f) ? t0 : 0.2f * t0;
            float t1 = af.y + arv.y; t1 = (t1 > 0.f) ? t1 : 0.2f * t1;
            e0p = __expf(t0);
            e1p = __expf(t1);
        }
        int i = 0;
        for (; i + 4 <= m; i += 4) {
            const int s0 = gsel | i, s1 = gsel | (i + 1);
            const int s2 = gsel | (i + 2), s3 = gsel | (i + 3);
            const int f0 = __shfl(vf, s0), f1 = __shfl(vf, s1);
            const int f2i = __shfl(vf, s2), f3 = __shfl(vf, s3);
            const uint32 h0 = hbp[(size_t)f0 * 64 + lane];
            const uint32 h1 = hbp[(size_t)f1 * 64 + lane];
            const uint32 h2 = hbp[(size_t)f2i * 64 + lane];
            const uint32 h3 = hbp[(size_t)f3 * 64 + lane];
            const float e00 = __shfl(e0p, s0), e10 = __shfl(e1p, s0);
            const float e01 = __shfl(e0p, s1), e11 = __shfl(e1p, s1);
            const float e02 = __shfl(e0p, s2), e12 = __shfl(e1p, s2);
            const float e03 = __shfl(e0p, s3), e13 = __shfl(e1p, s3);
            ax = fmaf(e00, __uint_as_float(h0 << 16), ax);
            ay = fmaf(e10, __uint_as_float(h0 & 0xFFFF0000u), ay);
            ds0 += e00; ds1 += e10;
            ax = fmaf(e01, __uint_as_float(h1 << 16), ax);
            ay = fmaf(e11, __uint_as_float(h1 & 0xFFFF0000u), ay);
            ds0 += e01; ds1 += e11;
            ax = fmaf(e02, __uint_as_float(h2 << 16), ax);
            ay = fmaf(e12, __uint_as_float(h2 & 0xFFFF0000u), ay);
            ds0 += e02; ds1 += e12;
            ax = fmaf(e03, __uint_as_float(h3 << 16), ax);
            ay = fmaf(e13, __uint_as_float(h3 & 0xFFFF0000u), ay);
            ds0 += e03; ds1 += e13;
        }
        for (; i < m; ++i) {
            const int s = gsel | i;
            const int f = __shfl(vf, s);
            const uint32 hv = hbp[(size_t)f * 64 + lane];
            const float e0 = __shfl(e0p, s), e1 = __shfl(e1p, s);
            ax = fmaf(e0, __uint_as_float(hv << 16), ax);
            ay = fmaf(e1, __uint_as_float(hv & 0xFFFF0000u), ay);
            ds0 += e0; ds1 += e1;
        }
    }
    const float inv0 = 1.0f / (ds0 + 1e-9f);
    const float inv1 = 1.0f / (ds1 + 1e-9f);
    out[n * F_OUT + lane]      = ax * inv0 + bias[lane];
    out[n * F_OUT + 64 + lane] = ay * inv1 + bias[64 + lane];
}

// ---------------------------------------------------------------------------
extern "C" void kernel_launch(void* const* d_in, const int* in_sizes, int n_in,
                              void* d_out, int out_size, void* d_ws, size_t ws_size,
                              hipStream_t stream)
{
    const float* x    = (const float*)d_in[0];
    const int*   ei   = (const int*)d_in[1];
    const float* W    = (const float*)d_in[2];
    const float* attl = (const float*)d_in[3];
    const float* attr = (const float*)d_in[4];
    const float* bias = (const float*)d_in[5];
    float* out = (float*)d_out;

    char* p = (char*)d_ws;
    auto carve = [&](size_t bytes) -> char* {
        char* q = p;
        p += (bytes + 255) & ~size_t(255);
        return q;
    };
    uint32* hbp       = (uint32*)carve((size_t)N_NODES * 64 * 4);          // 12.8 MB
    uint2*  priv      = (uint2*)carve((size_t)NBUCK * KA_GRID * CAPA * 8); // 25.7 MB
    int*    rec_from  = (int*)carve((size_t)N_EDGES * 4);                  // 3.2 MB
    ushort* WT_hi     = (ushort*)carve((size_t)F_IN * F_OUT * 2);
    ushort* WT_lo     = (ushort*)carve((size_t)F_IN * F_OUT * 2);
    float*  aLp       = (float*)carve((size_t)N_NODES * N_HEADS * 4);
    float*  aRp       = (float*)carve((size_t)N_NODES * N_HEADS * 4);
    int*    cnts      = (int*)carve((size_t)NBUCK * KA_GRID * 4);          // 200 KB
    int*    bsum      = (int*)carve(NBUCK * 4);
    int*    bucket_base = (int*)carve(NBUCK * 4);
    int*    count     = (int*)carve((size_t)N_NODES * 4);
    int*    offsets   = (int*)carve((size_t)N_NODES * 4);

    k_bin<<<KA_GRID, 256, 0, stream>>>(ei, W, WT_hi, WT_lo, priv, cnts);
    k_bsum<<<NBUCK, 256, 0, stream>>>(cnts, bsum);
    k_scan_base<<<1, 256, 0, stream>>>(bsum, bucket_base);
    k_build<<<NBUCK, 256, 0, stream>>>(priv, cnts, bucket_base,
                                       count, offsets, rec_from);
    k_gemm_mfma<<<(N_NODES + 63) / 64, 256, 0, stream>>>(x, WT_hi, WT_lo,
                                                         attl, attr, hbp, aLp, aRp);
    k_agg<<<(N_NODES + 3) / 4, 256, 0, stream>>>(rec_from, count, offsets,
                                                 aLp, aRp, hbp, bias, out);
}